// Round 11
// baseline (77.206 us; speedup 1.0000x reference)
//
#include <hip/hip_runtime.h>

#define GAMMA_F 267.52f
typedef float v4f __attribute__((ext_vector_type(4)));

constexpr int H = 256, W = 256, D = 128;
constexpr int WT = 8;          // w-lines per block
constexpr int HS = 8;          // h-rows marched per block
constexpr long long sW = D;
constexpr long long sH = (long long)W * D;
constexpr long long sB = (long long)H * (long long)W * D;

// Key identity: a_i*cos(phi_c) - a_r*sin(phi_c) = sum_n k_n * sin(phi_n - phi_c)
// (center term vanishes). So b_i needs NO sincos staging -- just raw phi
// neighborhoods and 6 __sinf per element. No LDS, no barriers: raw phi/lfs
// rows roll in registers (h taps), w+/-1 taps are global re-reads (L1/L2
// hits within the block), d+/-1 taps via 2-lane shuffles.
__global__ __launch_bounds__(256, 4) void lot_sindiff(
    const float* __restrict__ phi,
    const float* __restrict__ lfs,
    const float* __restrict__ mask,
    const float* __restrict__ TE,
    const float* __restrict__ B0,
    const float* __restrict__ kern,
    float* __restrict__ out_b,
    float* __restrict__ out_d)
{
    const int tid = threadIdx.x;
    const int q   = tid & 31;
    const int wr  = tid >> 5;
    const int w   = blockIdx.x * WT + wr;
    const int h0  = blockIdx.y * HS;
    const int b   = blockIdx.z;
    const int d0  = q * 4;

    const long long colBase = (long long)b * sB + (long long)w * sW + d0;

    // whole w-boundary column is zeros
    if (w == 0 || w == W - 1) {
        const v4f z = {0.f, 0.f, 0.f, 0.f};
        #pragma unroll
        for (int i = 0; i < HS; ++i) {
            const long long r = colBase + (long long)(h0 + i) * sH;
            __builtin_nontemporal_store(z, (v4f*)(out_b + r));
            __builtin_nontemporal_store(z, (v4f*)(out_d + r));
        }
        return;
    }

    const float kHc = kern[4];      // h +/- 1
    const float kWc = kern[10];     // w +/- 1
    const float kDc = kern[12];     // d +/- 1
    const float kCc = kern[13];     // center
    const float scale = -1.0f / (B0[0] * TE[b] * GAMMA_F);

    // guarded center-column quad load at row hh
    #define LD4(ptr, hh, DST)                                                \
    do {                                                                     \
        const int _h = (hh);                                                 \
        if (_h >= 0 && _h < H) {                                             \
            DST = *(const v4f*)((ptr) + colBase + (long long)_h * sH);       \
        } else {                                                             \
            DST = (v4f){0.f, 0.f, 0.f, 0.f};                                 \
        }                                                                    \
    } while (0)

    // rolling raw rows: h-1, h, h+1 for phi and lfs
    v4f Pm, Pc, Pp, Lm, Lc, Lp;
    LD4(phi, h0 - 1, Pm); LD4(phi, h0, Pc); LD4(phi, h0 + 1, Pp);
    LD4(lfs, h0 - 1, Lm); LD4(lfs, h0, Lc); LD4(lfs, h0 + 1, Lp);

    #pragma unroll
    for (int i = 0; i < HS; ++i) {
        const int h = h0 + i;
        const long long r = colBase + (long long)h * sH;

        // prefetch row h+2 (becomes Pp/Lp after rotation)
        v4f Pn, Ln;
        LD4(phi, h + 2, Pn);
        LD4(lfs, h + 2, Ln);

        if (h == 0 || h == H - 1) {
            const v4f z = {0.f, 0.f, 0.f, 0.f};
            __builtin_nontemporal_store(z, (v4f*)(out_b + r));
            __builtin_nontemporal_store(z, (v4f*)(out_d + r));
        } else {
            // w+/-1 taps: global re-reads (neighbor lines of this block -> cache)
            const v4f PwM = *(const v4f*)(phi + r - sW);
            const v4f PwP = *(const v4f*)(phi + r + sW);
            const v4f LwM = *(const v4f*)(lfs + r - sW);
            const v4f LwP = *(const v4f*)(lfs + r + sW);
            const v4f MK  = *(const v4f*)(mask + r);

            // d-edges from neighbor lanes (32-lane group = one w-line);
            // clamped lanes produce garbage only for d=0/d=127 (zeroed).
            const float pdm = __shfl_up(Pc.w, 1, 32);
            const float pdp = __shfl_down(Pc.x, 1, 32);
            const float ldm = __shfl_up(Lc.w, 1, 32);
            const float ldp = __shfl_down(Lc.x, 1, 32);

            const float px[6]  = {pdm, Pc.x, Pc.y, Pc.z, Pc.w, pdp};
            const float lx[6]  = {ldm, Lc.x, Lc.y, Lc.z, Lc.w, ldp};
            const float pmv[4] = {Pm.x, Pm.y, Pm.z, Pm.w};
            const float ppv[4] = {Pp.x, Pp.y, Pp.z, Pp.w};
            const float lmv[4] = {Lm.x, Lm.y, Lm.z, Lm.w};
            const float lpv[4] = {Lp.x, Lp.y, Lp.z, Lp.w};
            const float pwm[4] = {PwM.x, PwM.y, PwM.z, PwM.w};
            const float pwp[4] = {PwP.x, PwP.y, PwP.z, PwP.w};
            const float lwm[4] = {LwM.x, LwM.y, LwM.z, LwM.w};
            const float lwp[4] = {LwP.x, LwP.y, LwP.z, LwP.w};
            const float mkv[4] = {MK.x, MK.y, MK.z, MK.w};

            float ob[4], od[4];
            #pragma unroll
            for (int j = 0; j < 4; ++j) {
                const float c = px[j + 1];
                const float s =
                      kDc * (__sinf(px[j]  - c) + __sinf(px[j + 2] - c))
                    + kWc * (__sinf(pwm[j] - c) + __sinf(pwp[j]    - c))
                    + kHc * (__sinf(pmv[j] - c) + __sinf(ppv[j]    - c));
                float bi = s * mkv[j] * scale;

                const float lap = kCc * lx[j + 1]
                    + kDc * (lx[j] + lx[j + 2])
                    + kWc * (lwm[j] + lwp[j])
                    + kHc * (lmv[j] + lpv[j]);
                float dv = lap * mkv[j];

                const int d = d0 + j;
                if (d == 0 || d == D - 1) { bi = 0.f; dv = 0.f; }
                ob[j] = bi; od[j] = dv;
            }
            const v4f vb = {ob[0], ob[1], ob[2], ob[3]};
            const v4f vd = {od[0], od[1], od[2], od[3]};
            __builtin_nontemporal_store(vb, (v4f*)(out_b + r));
            __builtin_nontemporal_store(vd, (v4f*)(out_d + r));
        }

        // rotate raw rows (register copies only)
        Pm = Pc; Pc = Pp; Pp = Pn;
        Lm = Lc; Lc = Lp; Lp = Ln;
    }

    #undef LD4
}

extern "C" void kernel_launch(void* const* d_in, const int* in_sizes, int n_in,
                              void* d_out, int out_size, void* d_ws, size_t ws_size,
                              hipStream_t stream) {
    const float* phi  = (const float*)d_in[0];
    const float* lfs  = (const float*)d_in[1];
    const float* mask = (const float*)d_in[2];
    const float* TE   = (const float*)d_in[3];
    const float* B0   = (const float*)d_in[4];
    const float* kern = (const float*)d_in[5];

    float* out_b = (float*)d_out;
    float* out_d = out_b + sB * 2;   // B=2, C=1

    dim3 grid(W / WT, H / HS, 2);    // 32 x 32 x 2 = 2048 blocks
    dim3 block(256);
    hipLaunchKernelGGL(lot_sindiff, grid, block, 0, stream,
                       phi, lfs, mask, TE, B0, kern, out_b, out_d);
}

// Round 12
// 59.774 us; speedup vs baseline: 1.2916x; 1.2916x over previous
//
#include <hip/hip_runtime.h>

#define GAMMA_F 267.52f
typedef float v4f __attribute__((ext_vector_type(4)));

constexpr int H = 256, W = 256, D = 128;
constexpr int WT = 8;          // w-lines per block
constexpr int HS = 16;         // h-rows marched per block
constexpr int LW = WT + 2;     // w-lines incl. halo
constexpr long long sW = D;
constexpr long long sH = (long long)W * D;
constexpr long long sB = (long long)H * (long long)W * D;

// R10 base + ONE change: XCD-chunked bijective block swizzle (T1).
// Default dispatch round-robins consecutive blocks across the 8 XCDs, so
// w-adjacent tiles (which share halo lines) never share an L2. Remap so each
// XCD owns 128 consecutive tiles in x-major order -> halo re-reads L2-hit.
__global__ __launch_bounds__(256, 4) void lot_lds_v8(
    const float* __restrict__ phi,
    const float* __restrict__ lfs,
    const float* __restrict__ mask,
    const float* __restrict__ TE,
    const float* __restrict__ B0,
    const float* __restrict__ kern,
    float* __restrict__ out_b,
    float* __restrict__ out_d)
{
    __shared__ float Ssin[3][LW][D];
    __shared__ float Scos[3][LW][D];

    // ---- XCD-chunked swizzle: nwg = 1024, 1024 % 8 == 0 -> bijective ----
    const int bid  = blockIdx.x;                 // flat 0..1023
    const int tile = (bid & 7) * 128 + (bid >> 3);
    const int bx   = tile & 31;                  // w-tile 0..31
    const int by   = (tile >> 5) & 15;           // h-tile 0..15
    const int bz   = tile >> 9;                  // batch 0..1

    const int tid = threadIdx.x;
    const int q   = tid & 31;
    const int wr  = tid >> 5;
    const int w0  = bx * WT;
    const int h0  = by * HS;
    const int b   = bz;
    const int w   = w0 + wr;
    const int d0  = q * 4;
    const int lwc = wr + 1;

    const long long colBase = (long long)b * sB + (long long)w * sW + d0;

    const float kHc = kern[4];      // h +/- 1
    const float kWc = kern[10];     // w +/- 1
    const float kDc = kern[12];     // d +/- 1
    const float kCc = kern[13];     // center
    const float scale = -1.0f / (B0[0] * TE[b] * GAMMA_F);

    const bool haloLo  = (wr == 0)      && (w0 > 0);
    const bool haloHi  = (wr == WT - 1) && (w0 + WT < W);
    const bool hasHalo = haloLo || haloHi;
    const long long haloOff = haloLo ? -sW : sW;
    const int  haloLw  = haloLo ? 0 : (LW - 1);

    const bool wInterior = (w > 0) && (w < W - 1);

    // LDS-only barrier: ds ops retired per-wave, then raw s_barrier.
    #define BAR()                                                            \
    do {                                                                     \
        asm volatile("s_waitcnt lgkmcnt(0)" ::: "memory");                   \
        __builtin_amdgcn_s_barrier();                                        \
    } while (0)

    #define PHI_LOAD(hh, P, PH)                                              \
    do {                                                                     \
        const int _h = (hh);                                                 \
        if (_h >= 0 && _h < H) {                                             \
            const long long _r = colBase + (long long)_h * sH;               \
            P = *(const v4f*)(phi + _r);                                     \
            if (hasHalo) PH = *(const v4f*)(phi + _r + haloOff);             \
        }                                                                    \
    } while (0)

    #define SINCOS_STORE(SLOT, P, PH, SN, CS)                                \
    do {                                                                     \
        const int _s = (SLOT);                                               \
        SN[0] = __sinf(P.x); SN[1] = __sinf(P.y);                            \
        SN[2] = __sinf(P.z); SN[3] = __sinf(P.w);                            \
        CS[0] = __cosf(P.x); CS[1] = __cosf(P.y);                            \
        CS[2] = __cosf(P.z); CS[3] = __cosf(P.w);                            \
        v4f _vs = {SN[0], SN[1], SN[2], SN[3]};                              \
        v4f _vc = {CS[0], CS[1], CS[2], CS[3]};                              \
        *(v4f*)&Ssin[_s][lwc][d0] = _vs;                                     \
        *(v4f*)&Scos[_s][lwc][d0] = _vc;                                     \
        if (hasHalo) {                                                       \
            v4f _hs = {__sinf(PH.x), __sinf(PH.y), __sinf(PH.z), __sinf(PH.w)}; \
            v4f _hc = {__cosf(PH.x), __cosf(PH.y), __cosf(PH.z), __cosf(PH.w)}; \
            *(v4f*)&Ssin[_s][haloLw][d0] = _hs;                              \
            *(v4f*)&Scos[_s][haloLw][d0] = _hc;                              \
        }                                                                    \
    } while (0)

    #define LFS_LOAD(hh, F)                                                  \
    do {                                                                     \
        const int _h = (hh);                                                 \
        if (_h >= 0 && _h < H) {                                             \
            const long long _r = colBase + (long long)_h * sH;               \
            const v4f _l = *(const v4f*)(lfs + _r);                          \
            F[1] = _l.x; F[2] = _l.y; F[3] = _l.z; F[4] = _l.w;              \
            F[0] = (d0 > 0)     ? lfs[_r - 1] : 0.f;                         \
            F[5] = (d0 + 4 < D) ? lfs[_r + 4] : 0.f;                         \
        } else {                                                             \
            _Pragma("unroll")                                                \
            for (int _j = 0; _j < 6; ++_j) F[_j] = 0.f;                      \
        }                                                                    \
    } while (0)

    #define ROW_LOAD(hh, LA, LB, MK)                                         \
    do {                                                                     \
        const int _h = (hh);                                                 \
        if (_h > 0 && _h < H - 1 && wInterior) {                             \
            const long long _r = colBase + (long long)_h * sH;               \
            LA = *(const v4f*)(lfs + _r - sW);                               \
            LB = *(const v4f*)(lfs + _r + sW);                               \
            MK = *(const v4f*)(mask + _r);                                   \
        }                                                                    \
    } while (0)

    v4f pN  = {0.f, 0.f, 0.f, 0.f}, pNH  = {0.f, 0.f, 0.f, 0.f};
    float snC[4], csC[4], snT[4], csT[4];
    float FA[6], FB[6], FC[6];
    v4f lwA = {0.f, 0.f, 0.f, 0.f}, lwB = {0.f, 0.f, 0.f, 0.f};
    v4f mkC = {0.f, 0.f, 0.f, 0.f};

    PHI_LOAD(h0 - 1, pN, pNH);
    SINCOS_STORE(0, pN, pNH, snT, csT);
    PHI_LOAD(h0, pN, pNH);
    SINCOS_STORE(1, pN, pNH, snC, csC);
    LFS_LOAD(h0 - 1, FA);
    LFS_LOAD(h0,     FB);
    PHI_LOAD(h0 + 1, pN, pNH);
    ROW_LOAD(h0, lwA, lwB, mkC);

    int sm = 0, sc = 1, sp = 2;

    for (int i = 0; i < HS; ++i) {
        const int h = h0 + i;

        SINCOS_STORE(sp, pN, pNH, snT, csT);
        LFS_LOAD(h + 1, FC);
        BAR();

        v4f pN2 = pN, pN2H = pNH;
        PHI_LOAD(h + 2, pN2, pN2H);
        v4f lwA2 = lwA, lwB2 = lwB, mk2 = mkC;
        ROW_LOAD(h + 1, lwA2, lwB2, mk2);

        const long long r = colBase + (long long)h * sH;
        if (h == 0 || h == H - 1 || !wInterior) {
            const v4f z = {0.f, 0.f, 0.f, 0.f};
            __builtin_nontemporal_store(z, (v4f*)(out_b + r));
            __builtin_nontemporal_store(z, (v4f*)(out_d + r));
        } else {
            const v4f swm = *(const v4f*)&Ssin[sc][lwc - 1][d0];
            const v4f swp = *(const v4f*)&Ssin[sc][lwc + 1][d0];
            const v4f shm = *(const v4f*)&Ssin[sm][lwc][d0];
            const v4f shp = *(const v4f*)&Ssin[sp][lwc][d0];
            const v4f cwm = *(const v4f*)&Scos[sc][lwc - 1][d0];
            const v4f cwp = *(const v4f*)&Scos[sc][lwc + 1][d0];
            const v4f chm = *(const v4f*)&Scos[sm][lwc][d0];
            const v4f chp = *(const v4f*)&Scos[sp][lwc][d0];

            const float snL = __shfl_up(snC[3], 1, 32);
            const float snR = __shfl_down(snC[0], 1, 32);
            const float csL = __shfl_up(csC[3], 1, 32);
            const float csR = __shfl_down(csC[0], 1, 32);
            const float snx[6] = {snL, snC[0], snC[1], snC[2], snC[3], snR};
            const float csx[6] = {csL, csC[0], csC[1], csC[2], csC[3], csR};

            const float lwv0[4] = {lwA.x, lwA.y, lwA.z, lwA.w};
            const float lwv1[4] = {lwB.x, lwB.y, lwB.z, lwB.w};
            const float mkv[4]  = {mkC.x, mkC.y, mkC.z, mkC.w};
            const float swmv[4] = {swm.x, swm.y, swm.z, swm.w};
            const float swpv[4] = {swp.x, swp.y, swp.z, swp.w};
            const float shmv[4] = {shm.x, shm.y, shm.z, shm.w};
            const float shpv[4] = {shp.x, shp.y, shp.z, shp.w};
            const float cwmv[4] = {cwm.x, cwm.y, cwm.z, cwm.w};
            const float cwpv[4] = {cwp.x, cwp.y, cwp.z, cwp.w};
            const float chmv[4] = {chm.x, chm.y, chm.z, chm.w};
            const float chpv[4] = {chp.x, chp.y, chp.z, chp.w};

            float ob[4], od[4];
            #pragma unroll
            for (int j = 0; j < 4; ++j) {
                const float se = snx[j + 1], ce = csx[j + 1];
                const float a_r = kCc * ce
                    + kDc * (csx[j] + csx[j + 2])
                    + kWc * (cwmv[j] + cwpv[j])
                    + kHc * (chmv[j] + chpv[j]);
                const float a_i = kCc * se
                    + kDc * (snx[j] + snx[j + 2])
                    + kWc * (swmv[j] + swpv[j])
                    + kHc * (shmv[j] + shpv[j]);
                float bi = (a_i * ce - a_r * se) * mkv[j] * scale;

                const float lap = kCc * FB[j + 1]
                    + kDc * (FB[j] + FB[j + 2])
                    + kWc * (lwv0[j] + lwv1[j])
                    + kHc * (FA[j + 1] + FC[j + 1]);
                float dv = lap * mkv[j];

                const int d = d0 + j;
                if (d == 0 || d == D - 1) { bi = 0.f; dv = 0.f; }
                ob[j] = bi; od[j] = dv;
            }
            const v4f vb = {ob[0], ob[1], ob[2], ob[3]};
            const v4f vd = {od[0], od[1], od[2], od[3]};
            __builtin_nontemporal_store(vb, (v4f*)(out_b + r));
            __builtin_nontemporal_store(vd, (v4f*)(out_d + r));
        }

        #pragma unroll
        for (int j2 = 0; j2 < 4; ++j2) { snC[j2] = snT[j2]; csC[j2] = csT[j2]; }
        #pragma unroll
        for (int j2 = 0; j2 < 6; ++j2) { FA[j2] = FB[j2]; FB[j2] = FC[j2]; }
        pN = pN2; pNH = pN2H;
        lwA = lwA2; lwB = lwB2; mkC = mk2;
        const int t = sm; sm = sc; sc = sp; sp = t;

        BAR();
    }

    #undef BAR
    #undef PHI_LOAD
    #undef SINCOS_STORE
    #undef LFS_LOAD
    #undef ROW_LOAD
}

extern "C" void kernel_launch(void* const* d_in, const int* in_sizes, int n_in,
                              void* d_out, int out_size, void* d_ws, size_t ws_size,
                              hipStream_t stream) {
    const float* phi  = (const float*)d_in[0];
    const float* lfs  = (const float*)d_in[1];
    const float* mask = (const float*)d_in[2];
    const float* TE   = (const float*)d_in[3];
    const float* B0   = (const float*)d_in[4];
    const float* kern = (const float*)d_in[5];

    float* out_b = (float*)d_out;
    float* out_d = out_b + sB * 2;   // B=2, C=1

    dim3 grid(1024);                 // flat; swizzle-decoded in kernel
    dim3 block(256);
    hipLaunchKernelGGL(lot_lds_v8, grid, block, 0, stream,
                       phi, lfs, mask, TE, B0, kern, out_b, out_d);
}